// Round 5
// baseline (803.183 us; speedup 1.0000x reference)
//
#include <hip/hip_runtime.h>
#include <hip/hip_bf16.h>
#include <math.h>

typedef __bf16 bf16;
typedef bf16 bf16x4 __attribute__((ext_vector_type(4)));
typedef bf16 bf16x8 __attribute__((ext_vector_type(8)));
typedef float f32x4 __attribute__((ext_vector_type(4)));

#define T_TOK 4096
#define DDIM  768
#define HDIM  2688
#define NEXP  8
#define RMAX  9216            // max padded pair rows
#define KHALF (HDIM / 2)      // 1344
#define NT1   (HDIM / 128)    // 21 col-tiles in gemm1
#define NT2   (DDIM / 256)    // 3 col-tiles in gemm2

__device__ __forceinline__ void async_copy16(const void* g, void* l) {
    __builtin_amdgcn_global_load_lds(
        (__attribute__((address_space(1))) void*)g,
        (__attribute__((address_space(3))) void*)l,
        16, 0, 0);
}

// ---------------- Router ----------------
__global__ void router_kernel(const float* __restrict__ x,
                              const float* __restrict__ gate_w,
                              const float* __restrict__ ebias,
                              int* __restrict__ ctrl,
                              int* __restrict__ tok_e,
                              float* __restrict__ tok_w,
                              float* __restrict__ zloss) {
    __shared__ float gw[NEXP * DDIM];
    int tid = threadIdx.x;
    for (int i = tid; i < NEXP * DDIM; i += 256) gw[i] = gate_w[i];
    __syncthreads();

    int wv = tid >> 6, lane = tid & 63;
    int t = blockIdx.x * 4 + wv;
    const float* xr = x + (size_t)t * DDIM;

    float xv[12];
#pragma unroll
    for (int j = 0; j < 12; ++j) xv[j] = xr[j * 64 + lane];

    float acc[NEXP];
#pragma unroll
    for (int e = 0; e < NEXP; ++e) {
        float a = 0.f;
#pragma unroll
        for (int j = 0; j < 12; ++j) a += xv[j] * gw[e * DDIM + j * 64 + lane];
        acc[e] = a;
    }
#pragma unroll
    for (int e = 0; e < NEXP; ++e) {
#pragma unroll
        for (int off = 32; off > 0; off >>= 1) acc[e] += __shfl_xor(acc[e], off);
    }

    if (lane == 0) {
        float b[NEXP];
#pragma unroll
        for (int e = 0; e < NEXP; ++e) b[e] = acc[e] + ebias[e];
        int i0 = 0;
#pragma unroll
        for (int e = 1; e < NEXP; ++e) if (b[e] > b[i0]) i0 = e;
        int i1 = (i0 == 0) ? 1 : 0;
        float b1 = b[i1];
#pragma unroll
        for (int e = 0; e < NEXP; ++e) if (e != i0 && b[e] > b1) { b1 = b[e]; i1 = e; }

        float l0 = acc[i0], l1 = acc[i1];
        float mx = fmaxf(l0, l1);
        float e0 = __expf(l0 - mx), e1 = __expf(l1 - mx);
        float inv = 1.f / (e0 + e1);
        tok_e[t * 2 + 0] = i0;
        tok_e[t * 2 + 1] = i1;
        tok_w[t * 2 + 0] = e0 * inv;
        tok_w[t * 2 + 1] = e1 * inv;
        atomicAdd(&ctrl[i0], 1);
        atomicAdd(&ctrl[i1], 1);

        float m8 = acc[0];
#pragma unroll
        for (int e = 1; e < NEXP; ++e) m8 = fmaxf(m8, acc[e]);
        float s = 0.f;
#pragma unroll
        for (int e = 0; e < NEXP; ++e) s += __expf(acc[e] - m8);
        float lse = m8 + __logf(s);
        atomicAdd(zloss, (1e-5f / (float)T_TOK) * lse * lse);
    }
}

__global__ void offsets_kernel(int* ctrl) {
    if (threadIdx.x == 0 && blockIdx.x == 0) {
        int off = 0;
        for (int e = 0; e < NEXP; ++e) {
            ctrl[16 + e] = off;
            off += (ctrl[e] + 127) & ~127;
        }
        ctrl[16 + NEXP] = off;
    }
}

// ---------------- Fused scatter + gather: slot assign + x -> Xg (bf16) ----------------
__global__ void scatter_gather_kernel(int* __restrict__ ctrl,
                                      const int* __restrict__ tok_e,
                                      const float* __restrict__ tok_w,
                                      int* __restrict__ pair_tok,
                                      float* __restrict__ pair_w,
                                      const float* __restrict__ x,
                                      bf16* __restrict__ Xg) {
    __shared__ int sp[2];
    int t = blockIdx.x;
    int tid = threadIdx.x;  // 192 threads
    if (tid < 2) {
        int e = tok_e[t * 2 + tid];
        int pos = ctrl[16 + e] + atomicAdd(&ctrl[8 + e], 1);
        pair_tok[pos] = t;
        pair_w[pos] = tok_w[t * 2 + tid];
        sp[tid] = pos;
    }
    __syncthreads();
    float4 v = *(const float4*)(x + (size_t)t * DDIM + tid * 4);
    bf16x4 o;
    o.x = (bf16)v.x; o.y = (bf16)v.y; o.z = (bf16)v.z; o.w = (bf16)v.w;
    *(bf16x4*)(Xg + (size_t)sp[0] * DDIM + tid * 4) = o;
    *(bf16x4*)(Xg + (size_t)sp[1] * DDIM + tid * 4) = o;
}

// ---------------- Weight transpose fp32->bf16 (float4 reads, bf16x4 writes) ----------------
__global__ void transpose_kernel(const float* __restrict__ wgp,
                                 const float* __restrict__ wup,
                                 const float* __restrict__ wdp,
                                 bf16* __restrict__ WgT,
                                 bf16* __restrict__ WuT,
                                 bf16* __restrict__ WdT) {
    __shared__ float tile[64][65];
    int m = blockIdx.y;
    int kind = m >> 3, e = m & 7;
    const float* src; bf16* dst; int R, C;
    if (kind == 0)      { src = wgp + (size_t)e * DDIM * HDIM; dst = WgT + (size_t)e * HDIM * DDIM; R = DDIM; C = HDIM; }
    else if (kind == 1) { src = wup + (size_t)e * DDIM * HDIM; dst = WuT + (size_t)e * HDIM * DDIM; R = DDIM; C = HDIM; }
    else                { src = wdp + (size_t)e * HDIM * DDIM; dst = WdT + (size_t)e * DDIM * HDIM; R = HDIM; C = DDIM; }

    int nR = R >> 6;
    int t = blockIdx.x;
    int tr = t % nR, tc = t / nR;
    int r0 = tr << 6, c0 = tc << 6;
    int tid = threadIdx.x;           // 256
    int l16 = tid & 15, g16 = tid >> 4;   // 16 rows per pass

#pragma unroll
    for (int p = 0; p < 4; ++p) {
        int r = p * 16 + g16;
        float4 v = *(const float4*)(src + (size_t)(r0 + r) * C + c0 + l16 * 4);
        tile[r][l16 * 4 + 0] = v.x;
        tile[r][l16 * 4 + 1] = v.y;
        tile[r][l16 * 4 + 2] = v.z;
        tile[r][l16 * 4 + 3] = v.w;
    }
    __syncthreads();
#pragma unroll
    for (int p = 0; p < 4; ++p) {
        int c = p * 16 + g16;
        bf16x4 o;
        o.x = (bf16)tile[l16 * 4 + 0][c];
        o.y = (bf16)tile[l16 * 4 + 1][c];
        o.z = (bf16)tile[l16 * 4 + 2][c];
        o.w = (bf16)tile[l16 * 4 + 3][c];
        *(bf16x4*)(dst + (size_t)(c0 + c) * R + r0 + l16 * 4) = o;
    }
}

// ---------------- GEMM1: G = silu(Xg@Wg) * (Xg@Wu) ----------------
// 512 threads (8 waves). Tile: M=128 x N=128 (both gate & up). BK=64, dbuf (96KB).
// Grid id: e = id&7 (XCD pin), mtile = (id>>3)&31, nt = id>>8.
__launch_bounds__(512, 2)
__global__ void gemm1_kernel(const bf16* __restrict__ Xg,
                             const bf16* __restrict__ WgT,
                             const bf16* __restrict__ WuT,
                             const int* __restrict__ ctrl,
                             bf16* __restrict__ G) {
    int id = blockIdx.x;
    int e = id & 7;
    int mtile = (id >> 3) & 31;
    int nt = id >> 8;
    const int* offs = ctrl + 16;
    int off_e = offs[e];
    int pad_cnt = offs[e + 1] - off_e;
    if (mtile * 128 >= pad_cnt) return;
    int row0 = off_e + mtile * 128;
    int n0 = nt * 128;

    // each buffer: 128 rows x 64 k bf16 = 16 KB (8192 elts)
    __shared__ __align__(16) bf16 sA[2 * 8192];
    __shared__ __align__(16) bf16 sBg[2 * 8192];
    __shared__ __align__(16) bf16 sBu[2 * 8192];

    int tid = threadIdx.x;
    int wv = tid >> 6, lane = tid & 63;
    int wm = wv & 1, wq = wv >> 1;        // wm: 64-row half; wq: 32-col quarter
    int quad = lane >> 4, lm = lane & 15;

    // staging chunks u (row=u>>3, seg=u&7); source chunk = seg ^ (row&7)
    int r1 = tid >> 3, s1 = ((tid & 7) ^ (r1 & 7)) * 8;
    int u2 = tid + 512;
    int r2 = u2 >> 3, s2 = ((u2 & 7) ^ (r2 & 7)) * 8;

    const bf16* A1 = Xg + (size_t)(row0 + r1) * DDIM + s1;
    const bf16* A2 = Xg + (size_t)(row0 + r2) * DDIM + s2;
    const bf16* Bg1 = WgT + ((size_t)e * HDIM + n0 + r1) * DDIM + s1;
    const bf16* Bg2 = WgT + ((size_t)e * HDIM + n0 + r2) * DDIM + s2;
    const bf16* Bu1 = WuT + ((size_t)e * HDIM + n0 + r1) * DDIM + s1;
    const bf16* Bu2 = WuT + ((size_t)e * HDIM + n0 + r2) * DDIM + s2;

    bf16* dA1 = sA + tid * 8;       bf16* dA2 = sA + u2 * 8;
    bf16* dBg1 = sBg + tid * 8;     bf16* dBg2 = sBg + u2 * 8;
    bf16* dBu1 = sBu + tid * 8;     bf16* dBu2 = sBu + u2 * 8;

    f32x4 accg[4][2], accu[4][2];
#pragma unroll
    for (int mi = 0; mi < 4; ++mi)
#pragma unroll
        for (int ni = 0; ni < 2; ++ni) { accg[mi][ni] = 0.f; accu[mi][ni] = 0.f; }

    async_copy16(A1, dA1);  async_copy16(A2, dA2);
    async_copy16(Bg1, dBg1); async_copy16(Bg2, dBg2);
    async_copy16(Bu1, dBu1); async_copy16(Bu2, dBu2);

    const int NK = DDIM / 64;  // 12
#pragma unroll
    for (int ks = 0; ks < NK; ++ks) {
        __syncthreads();
        if (ks + 1 < NK) {
            int kk = (ks + 1) * 64;
            int bo = ((ks + 1) & 1) * 8192;
            async_copy16(A1 + kk, dA1 + bo);   async_copy16(A2 + kk, dA2 + bo);
            async_copy16(Bg1 + kk, dBg1 + bo); async_copy16(Bg2 + kk, dBg2 + bo);
            async_copy16(Bu1 + kk, dBu1 + bo); async_copy16(Bu2 + kk, dBu2 + bo);
        }
        int bo = (ks & 1) * 8192;
#pragma unroll
        for (int kb = 0; kb < 2; ++kb) {
            bf16x8 af[4], bg[2], bu[2];
#pragma unroll
            for (int mi = 0; mi < 4; ++mi) {
                int r = wm * 64 + mi * 16 + lm;
                int c = kb * 4 + quad;
                af[mi] = *(const bf16x8*)(sA + bo + r * 64 + ((c ^ (r & 7)) * 8));
            }
#pragma unroll
            for (int ni = 0; ni < 2; ++ni) {
                int rn = wq * 32 + ni * 16 + lm;
                int c = kb * 4 + quad;
                bg[ni] = *(const bf16x8*)(sBg + bo + rn * 64 + ((c ^ (rn & 7)) * 8));
                bu[ni] = *(const bf16x8*)(sBu + bo + rn * 64 + ((c ^ (rn & 7)) * 8));
            }
#pragma unroll
            for (int mi = 0; mi < 4; ++mi)
#pragma unroll
                for (int ni = 0; ni < 2; ++ni) {
                    accg[mi][ni] = __builtin_amdgcn_mfma_f32_16x16x32_bf16(af[mi], bg[ni], accg[mi][ni], 0, 0, 0);
                    accu[mi][ni] = __builtin_amdgcn_mfma_f32_16x16x32_bf16(af[mi], bu[ni], accu[mi][ni], 0, 0, 0);
                }
        }
    }

#pragma unroll
    for (int mi = 0; mi < 4; ++mi)
#pragma unroll
        for (int ni = 0; ni < 2; ++ni)
#pragma unroll
            for (int r = 0; r < 4; ++r) {
                float gg = accg[mi][ni][r];
                float u = accu[mi][ni][r];
                float val = (gg / (1.f + __expf(-gg))) * u;
                int rl = wm * 64 + mi * 16 + quad * 4 + r;
                int col = n0 + wq * 32 + ni * 16 + lm;
                G[(size_t)(row0 + rl) * HDIM + col] = (bf16)val;
            }
}

// ---------------- GEMM2: out += w * (G @ Wd), K-split 2, fused weighted atomic scatter ----------------
// 512 threads. Tile M=128 x N=256. BK=64, dbuf (96KB).
__launch_bounds__(512, 2)
__global__ void gemm2_kernel(const bf16* __restrict__ G,
                             const bf16* __restrict__ WdT,
                             const int* __restrict__ ctrl,
                             const int* __restrict__ pair_tok,
                             const float* __restrict__ pair_w,
                             float* __restrict__ out) {
    int id = blockIdx.x;
    int e = id & 7;
    int mtile = (id >> 3) & 31;
    int rest = id >> 8;
    int s = rest & 1, nt = rest >> 1;
    const int* offs = ctrl + 16;
    int off_e = offs[e];
    int cnt_e = ctrl[e];
    int pad_cnt = offs[e + 1] - off_e;
    if (mtile * 128 >= pad_cnt) return;
    int row0 = off_e + mtile * 128;
    int n0 = nt * 256;

    __shared__ __align__(16) bf16 sA[2 * 8192];    // 128 x 64
    __shared__ __align__(16) bf16 sB[2 * 16384];   // 256 x 64

    int tid = threadIdx.x;
    int wv = tid >> 6, lane = tid & 63;
    int wm = wv & 1, wq = wv >> 1;       // wm: 64-row half; wq: 64-col quarter
    int quad = lane >> 4, lm = lane & 15;

    int r1 = tid >> 3, s1 = ((tid & 7) ^ (r1 & 7)) * 8;
    int u2 = tid + 512;
    int r2 = u2 >> 3, s2 = ((u2 & 7) ^ (r2 & 7)) * 8;
    int u3 = tid + 1024;
    int r3 = u3 >> 3, s3 = ((u3 & 7) ^ (r3 & 7)) * 8;
    int u4 = tid + 1536;
    int r4 = u4 >> 3, s4 = ((u4 & 7) ^ (r4 & 7)) * 8;

    size_t kbase = (size_t)s * KHALF;
    const bf16* A1 = G + (size_t)(row0 + r1) * HDIM + kbase + s1;
    const bf16* A2 = G + (size_t)(row0 + r2) * HDIM + kbase + s2;
    const bf16* B1 = WdT + ((size_t)e * DDIM + n0 + r1) * HDIM + kbase + s1;
    const bf16* B2 = WdT + ((size_t)e * DDIM + n0 + r2) * HDIM + kbase + s2;
    const bf16* B3 = WdT + ((size_t)e * DDIM + n0 + r3) * HDIM + kbase + s3;
    const bf16* B4 = WdT + ((size_t)e * DDIM + n0 + r4) * HDIM + kbase + s4;

    bf16* dA1 = sA + tid * 8;  bf16* dA2 = sA + u2 * 8;
    bf16* dB1 = sB + tid * 8;  bf16* dB2 = sB + u2 * 8;
    bf16* dB3 = sB + u3 * 8;   bf16* dB4 = sB + u4 * 8;

    f32x4 acc[4][4];
#pragma unroll
    for (int mi = 0; mi < 4; ++mi)
#pragma unroll
        for (int ni = 0; ni < 4; ++ni) acc[mi][ni] = 0.f;

    async_copy16(A1, dA1); async_copy16(A2, dA2);
    async_copy16(B1, dB1); async_copy16(B2, dB2);
    async_copy16(B3, dB3); async_copy16(B4, dB4);

    const int NK = KHALF / 64;  // 21
#pragma unroll
    for (int ks = 0; ks < NK; ++ks) {
        __syncthreads();
        if (ks + 1 < NK) {
            int kk = (ks + 1) * 64;
            int boA = ((ks + 1) & 1) * 8192;
            int boB = ((ks + 1) & 1) * 16384;
            async_copy16(A1 + kk, dA1 + boA); async_copy16(A2 + kk, dA2 + boA);
            async_copy16(B1 + kk, dB1 + boB); async_copy16(B2 + kk, dB2 + boB);
            async_copy16(B3 + kk, dB3 + boB); async_copy16(B4 + kk, dB4 + boB);
        }
        int boA = (ks & 1) * 8192;
        int boB = (ks & 1) * 16384;
#pragma unroll
        for (int kb = 0; kb < 2; ++kb) {
            bf16x8 af[4], bb[4];
#pragma unroll
            for (int mi = 0; mi < 4; ++mi) {
                int r = wm * 64 + mi * 16 + lm;
                int c = kb * 4 + quad;
                af[mi] = *(const bf16x8*)(sA + boA + r * 64 + ((c ^ (r & 7)) * 8));
            }
#pragma unroll
            for (int ni = 0; ni < 4; ++ni) {
                int rn = wq * 64 + ni * 16 + lm;
                int c = kb * 4 + quad;
                bb[ni] = *(const bf16x8*)(sB + boB + rn * 64 + ((c ^ (rn & 7)) * 8));
            }
#pragma unroll
            for (int mi = 0; mi < 4; ++mi)
#pragma unroll
                for (int ni = 0; ni < 4; ++ni)
                    acc[mi][ni] = __builtin_amdgcn_mfma_f32_16x16x32_bf16(af[mi], bb[ni], acc[mi][ni], 0, 0, 0);
        }
    }

#pragma unroll
    for (int mi = 0; mi < 4; ++mi)
#pragma unroll
        for (int r = 0; r < 4; ++r) {
            int rl = wm * 64 + mi * 16 + quad * 4 + r;
            if (mtile * 128 + rl < cnt_e) {
                int rabs = row0 + rl;
                int tok = pair_tok[rabs];
                float wt = pair_w[rabs];
#pragma unroll
                for (int ni = 0; ni < 4; ++ni) {
                    int col = n0 + wq * 64 + ni * 16 + lm;
                    atomicAdd(out + (size_t)tok * DDIM + col, wt * acc[mi][ni][r]);
                }
            }
        }
}

extern "C" void kernel_launch(void* const* d_in, const int* in_sizes, int n_in,
                              void* d_out, int out_size, void* d_ws, size_t ws_size,
                              hipStream_t stream) {
    const float* x      = (const float*)d_in[0];
    const float* gate_w = (const float*)d_in[1];
    const float* ebias  = (const float*)d_in[2];
    const float* wgp    = (const float*)d_in[3];
    const float* wup    = (const float*)d_in[4];
    const float* wdp    = (const float*)d_in[5];
    float* out = (float*)d_out;

    int*   ctrl     = (int*)d_ws;                          // 128 ints
    int*   tok_e    = ctrl + 128;                          // 2T
    float* tok_w    = (float*)(tok_e + 2 * T_TOK);         // 2T
    int*   pair_tok = (int*)(tok_w + 2 * T_TOK);           // RMAX
    float* pair_w   = (float*)(pair_tok + RMAX);           // RMAX
    bf16*  Xg       = (bf16*)(pair_w + RMAX);              // RMAX*768
    bf16*  G        = Xg + (size_t)RMAX * DDIM;            // RMAX*2688
    bf16*  WgT      = G + (size_t)RMAX * HDIM;
    bf16*  WuT      = WgT + (size_t)NEXP * DDIM * HDIM;
    bf16*  WdT      = WuT + (size_t)NEXP * DDIM * HDIM;

    hipMemsetAsync(d_out, 0, (size_t)(T_TOK * DDIM + 1) * sizeof(float), stream);
    hipMemsetAsync(d_ws, 0, 512, stream);                  // ctrl

    router_kernel<<<T_TOK / 4, 256, 0, stream>>>(x, gate_w, ebias, ctrl, tok_e, tok_w,
                                                 out + (size_t)T_TOK * DDIM);
    offsets_kernel<<<1, 64, 0, stream>>>(ctrl);
    scatter_gather_kernel<<<T_TOK, 192, 0, stream>>>(ctrl, tok_e, tok_w, pair_tok, pair_w, x, Xg);
    transpose_kernel<<<dim3(504, 24), 256, 0, stream>>>(wgp, wup, wdp, WgT, WuT, WdT);
    gemm1_kernel<<<8 * 32 * NT1, 512, 0, stream>>>(Xg, WgT, WuT, ctrl, G);
    gemm2_kernel<<<8 * 32 * 2 * NT2, 512, 0, stream>>>(G, WdT, ctrl, pair_tok, pair_w, out);
}